// Round 3
// baseline (278.695 us; speedup 1.0000x reference)
//
#include <hip/hip_runtime.h>
#include <hip/hip_bf16.h>
#include <math.h>

#define A_TOT 8400
#define B_N   2
#define T_N   100
#define C_N   80
#define E_N   32
#define MH_N  64
#define MW_N  64
#define ROW_N 8363          // 4 + 80 + 85 + 4096 + 4098
#define EPSF  1e-9f

// Single emitted copy shared by both kernels -> bitwise-identical tmat values.
__device__ __attribute__((noinline)) float2 tmat_eval(
    float gx1, float gy1, float gx2, float gy2,
    float ax,  float ay,
    float px1, float py1, float px2, float py2,
    float cl) {
  float ix1 = fmaxf(gx1,px1), iy1 = fmaxf(gy1,py1);
  float ix2 = fminf(gx2,px2), iy2 = fminf(gy2,py2);
  float inter = fmaxf(ix2-ix1,0.f) * fmaxf(iy2-iy1,0.f);
  float wg = gx2-gx1, hg = gy2-gy1, wp = px2-px1, hp = py2-py1;
  float uni = wg*hg + wp*hp - inter + EPSF;
  float iou = inter / uni;
  float cw = fmaxf(gx2,px2) - fminf(gx1,px1);
  float ch = fmaxf(gy2,py2) - fminf(gy1,py1);
  float c2 = cw*cw + ch*ch + EPSF;
  float dx = gx1+gx2-px1-px2, dy = gy1+gy2-py1-py2;
  float rho2 = (dx*dx + dy*dy) * 0.25f;
  float da = atanf(wg/(hg+EPSF)) - atanf(wp/(hp+EPSF));
  float v  = 0.4052847345693511f * da * da;     // 4/pi^2
  float alpha = v / (1.f - iou + v + EPSF);
  float ciou = iou - rho2/c2 - alpha*v;
  float iouc = fminf(fmaxf(ciou, 0.f), 1.f);

  float tm = 0.f;
  if (ax > gx1 && ay > gy1 && ax < gx2 && ay < gy2) {   // strict grid mask
    float cp = 1.f / (1.f + expf(-cl));
    float i2 = iouc * iouc;
    tm = i2*i2*i2 * sqrtf(cp);                 // iou^6 * cls^0.5
  }
  return make_float2(tm, iouc);
}

// ---- kernel 1: per (b,t) block: kth (10th largest tmat), max tmat, max iou
__global__ __launch_bounds__(256) void k_topk(
    const float* __restrict__ cls_logits, const float* __restrict__ pred_boxes,
    const float* __restrict__ target_bbox, const int* __restrict__ target_cls,
    const float* __restrict__ anchors,
    float* __restrict__ kth, float* __restrict__ maxt, float* __restrict__ maxiou) {
  int bt = blockIdx.x;
  int b  = bt / T_N;
  int tid = threadIdx.x;
  __shared__ float vals[A_TOT];
  __shared__ float red[256];
  __shared__ int   sidx;

  float gx1 = target_bbox[bt*4+0], gy1 = target_bbox[bt*4+1];
  float gx2 = target_bbox[bt*4+2], gy2 = target_bbox[bt*4+3];
  int   tc  = target_cls[bt];

  float lm = 0.f, li = 0.f;                    // tmat,iou_clipped are >= 0
  for (int a = tid; a < A_TOT; a += 256) {
    float4 pb = *(const float4*)(pred_boxes + ((size_t)(b*A_TOT+a))*4);
    float ax = anchors[a*2+0], ay = anchors[a*2+1];
    float cl = cls_logits[((size_t)(b*A_TOT+a))*C_N + tc];
    float2 r = tmat_eval(gx1,gy1,gx2,gy2, ax,ay, pb.x,pb.y,pb.z,pb.w, cl);
    vals[a] = r.x;
    lm = fmaxf(lm, r.x);
    li = fmaxf(li, r.y);
  }
  red[tid] = lm; __syncthreads();
  for (int s = 128; s > 0; s >>= 1) { if (tid < s) red[tid] = fmaxf(red[tid], red[tid+s]); __syncthreads(); }
  if (tid == 0) maxt[bt] = red[0];
  __syncthreads();
  red[tid] = li; __syncthreads();
  for (int s = 128; s > 0; s >>= 1) { if (tid < s) red[tid] = fmaxf(red[tid], red[tid+s]); __syncthreads(); }
  if (tid == 0) maxiou[bt] = red[0];

  float cur = 0.f;
  for (int k = 0; k < 10; k++) {
    __syncthreads();
    float l = -1e30f;
    for (int i = tid; i < A_TOT; i += 256) l = fmaxf(l, vals[i]);
    red[tid] = l; __syncthreads();
    for (int s = 128; s > 0; s >>= 1) { if (tid < s) red[tid] = fmaxf(red[tid], red[tid+s]); __syncthreads(); }
    float m = red[0];
    if (tid == 0) sidx = 0x7fffffff;
    __syncthreads();
    for (int i = tid; i < A_TOT; i += 256) if (vals[i] == m) atomicMin(&sidx, i);
    __syncthreads();
    if (tid == 0 && sidx != 0x7fffffff) vals[sidx] = -1e30f;  // remove ONE instance
    cur = m;
  }
  if (tid == 0) kth[bt] = cur;
}

// ---- kernel 2: per (b,a): unique_idx, valid, norm_g (recompute tmat row)
__global__ __launch_bounds__(256) void k_assign(
    const float* __restrict__ cls_logits, const float* __restrict__ pred_boxes,
    const float* __restrict__ target_bbox, const int* __restrict__ target_cls,
    const float* __restrict__ anchors, const float* __restrict__ kth,
    const float* __restrict__ maxt, const float* __restrict__ maxiou,
    int* __restrict__ uidx, float* __restrict__ validf, float* __restrict__ normg) {
  int b   = blockIdx.y;
  int tid = threadIdx.x;
  int a   = blockIdx.x * 256 + tid;
  __shared__ float tbb[T_N*4];
  __shared__ int   tcs[T_N];
  __shared__ float kths[T_N];
  if (tid < T_N) { tcs[tid] = target_cls[b*T_N+tid]; kths[tid] = kth[b*T_N+tid]; }
  for (int i = tid; i < T_N*4; i += 256) tbb[i] = target_bbox[b*T_N*4 + i];
  __syncthreads();
  if (a >= A_TOT) return;

  float ax = anchors[a*2+0], ay = anchors[a*2+1];
  float4 pb = *(const float4*)(pred_boxes + ((size_t)(b*A_TOT+a))*4);
  const float* crow = cls_logits + ((size_t)(b*A_TOT+a))*C_N;

  float best = 0.f; int u = 0; int any = 0;
  for (int t = 0; t < T_N; t++) {
    float2 r = tmat_eval(tbb[4*t],tbb[4*t+1],tbb[4*t+2],tbb[4*t+3],
                         ax,ay, pb.x,pb.y,pb.z,pb.w, crow[tcs[t]]);
    float v = r.x;
    if (v > 0.f && v >= kths[t]) {            // topk_targets condition
      any = 1;
      if (v > best) { best = v; u = t; }      // argmax, first occurrence on ties
    }
  }
  int bu = b*T_N + u;
  float ng = any ? best / (maxt[bu] + EPSF) * maxiou[bu] : 0.f;  // only used when valid
  int idx = b*A_TOT + a;
  uidx[idx]   = u;
  validf[idx] = any ? 1.f : 0.f;
  normg[idx]  = ng;
}

// ---- kernel 3: assemble full 8363-wide output row per (b,a), f32 out ------
__global__ __launch_bounds__(256) void k_write(
    const float* __restrict__ cls_logits, const float* __restrict__ pred_boxes,
    const float* __restrict__ mask_embs,  const float* __restrict__ protos,
    const int*   __restrict__ target_cls, const float* __restrict__ target_bbox,
    const float* __restrict__ target_masks, const float* __restrict__ scalers,
    const int* __restrict__ uidx, const float* __restrict__ validf, const float* __restrict__ normg,
    float* __restrict__ out) {
  int ba = blockIdx.x;                        // b*A + a
  int b = ba / A_TOT;
  int a = ba - b * A_TOT;
  int tid = threadIdx.x;
  __shared__ float semb[E_N];

  int   u   = uidx[ba];
  float vld = validf[ba];
  float ng  = normg[ba];
  float s   = scalers[a];
  int bu = b * T_N + u;
  float tb0 = target_bbox[bu*4+0], tb1 = target_bbox[bu*4+1];
  float tb2 = target_bbox[bu*4+2], tb3 = target_bbox[bu*4+3];
  int ct = target_cls[bu];
  if (tid < E_N) semb[tid] = mask_embs[(size_t)ba * E_N + tid];
  __syncthreads();

  size_t base = (size_t)ba * ROW_N;

  // [0:4] boxes_scaled, [4:84] cls_logits, [84:88] align_bbox/s, [88] valid,
  // [89:169] align_cls, [4265] area, [4266] valid
  if (tid < 171) {
    int pos; float val;
    if (tid < 4)        { pos = tid; val = pred_boxes[(size_t)ba*4 + tid] / s; }
    else if (tid < 84)  { pos = tid; val = cls_logits[(size_t)ba*C_N + (tid-4)]; }
    else if (tid < 88)  { int j = tid-84; float t = (j==0)?tb0:((j==1)?tb1:((j==2)?tb2:tb3));
                          pos = tid; val = t / s; }
    else if (tid == 88) { pos = 88; val = vld; }
    else if (tid < 169) { int c = tid-89; pos = tid; val = (vld > 0.5f && c == ct) ? ng : 0.f; }
    else if (tid == 169){ pos = 4265; val = (tb2-tb0)*(tb3-tb1) / (640.f*640.f); }
    else                { pos = 4266; val = vld; }
    out[base + pos] = val;
  }

  // seg_pred [169:4265], align_seg [4267:8363]
  bool vb = vld > 0.5f;
  float x1s = tb0 * 0.1f, y1s = tb1 * 0.1f;    // 64/640
  float x2s = tb2 * 0.1f, y2s = tb3 * 0.1f;
  for (int p = tid; p < MH_N * MW_N; p += 256) {
    int h = p >> 6, w = p & 63;
    float fh = (float)h, fw = (float)w;
    float sp = 0.f, as = 0.f;
    if (vb && fh >= y1s && fh < y2s && fw >= x1s && fw < x2s) {
      const float* pr = protos + ((size_t)((b*MH_N + h)*MW_N + w)) * E_N;
      float acc = 0.f;
      #pragma unroll
      for (int e = 0; e < E_N; e++) acc += semb[e] * pr[e];
      sp = 1.f / (1.f + expf(-acc));
      as = target_masks[((size_t)((b*MH_N + h)*MW_N + w)) * T_N + u];
    }
    out[base + 169  + p] = sp;
    out[base + 4267 + p] = as;
  }
}

extern "C" void kernel_launch(void* const* d_in, const int* in_sizes, int n_in,
                              void* d_out, int out_size, void* d_ws, size_t ws_size,
                              hipStream_t stream) {
  const float* cls_logits   = (const float*)d_in[0];
  const float* pred_boxes   = (const float*)d_in[1];
  const float* mask_embs    = (const float*)d_in[2];
  const float* protos       = (const float*)d_in[3];
  const int*   target_cls   = (const int*)  d_in[4];
  const float* target_bbox  = (const float*)d_in[5];
  const float* target_masks = (const float*)d_in[6];
  const float* anchors      = (const float*)d_in[7];
  const float* scalers      = (const float*)d_in[8];
  float* out = (float*)d_out;

  // tiny workspace: 204 KB total
  float* ws     = (float*)d_ws;
  float* kth    = ws;                              // 200
  float* maxt   = kth    + B_N*T_N;                // 200
  float* maxiou = maxt   + B_N*T_N;                // 200
  float* validf = maxiou + B_N*T_N;                // 16800
  float* normg  = validf + (size_t)B_N*A_TOT;      // 16800
  int*   uidx   = (int*)(normg + (size_t)B_N*A_TOT); // 16800

  k_topk<<<B_N*T_N, 256, 0, stream>>>(cls_logits, pred_boxes, target_bbox,
                                      target_cls, anchors, kth, maxt, maxiou);
  dim3 gAsn((A_TOT + 255)/256, B_N);
  k_assign<<<gAsn, 256, 0, stream>>>(cls_logits, pred_boxes, target_bbox, target_cls,
                                     anchors, kth, maxt, maxiou, uidx, validf, normg);
  k_write<<<B_N*A_TOT, 256, 0, stream>>>(cls_logits, pred_boxes, mask_embs, protos,
                                         target_cls, target_bbox, target_masks, scalers,
                                         uidx, validf, normg, out);
}